// Round 1
// baseline (957.198 us; speedup 1.0000x reference)
//
#include <hip/hip_runtime.h>
#include <hip/hip_bf16.h>
#include <stdint.h>

// DRNN_75204877353433: windowed bidirectional GRU (W=15) + BN + MLP + masked maxpool + linear
// B=32 S=512 W=15 E=300 H=256 V=50000 C=2, G=3H=768

typedef unsigned short u16;
typedef unsigned int u32;
typedef float f32x16 __attribute__((ext_vector_type(16)));
typedef float f32x4  __attribute__((ext_vector_type(4)));
typedef short bf16x8 __attribute__((ext_vector_type(8)));

#define MFMA32 __builtin_amdgcn_mfma_f32_32x32x16_bf16

#define NB 32
#define NS 512
#define NW 15
#define NE 300
#define NH 256
#define NG 768
#define NCELL (NB*NS)   // 16384
#define EPAD 320        // E padded to multiple of 16
#define MRE 32          // rows per block in eproj/mlp
#define HS 264          // h_lds row stride (u16)

__device__ __forceinline__ float bf2f(u16 u){
    union { unsigned int i; float f; } v; v.i = ((unsigned int)u) << 16; return v.f;
}
__device__ __forceinline__ u16 f2bf(float f){
    union { float f; unsigned int i; } v; v.f = f;
    unsigned int x = v.i;
    x += 0x7fffu + ((x >> 16) & 1u);   // RNE
    return (u16)(x >> 16);
}
__device__ __forceinline__ u16 f2bf_rh(float f){   // round-half-up, 2 VALU ops
    return (u16)((__float_as_uint(f) + 0x8000u) >> 16);
}
__device__ __forceinline__ unsigned fkey(float f){   // order-preserving float->uint map
    unsigned b = __float_as_uint(f);
    return b ^ ((b & 0x80000000u) ? 0xFFFFFFFFu : 0x80000000u);
}

// ---- hw transcendental gate math: short chains, saturating edge behavior ----
// sigm(x) = 1/(1+2^(-x*log2e)); exp2 overflow->inf -> rcp->0, underflow->0 -> rcp(1)=1
__device__ __forceinline__ float sigm_hw(float x){
    return __builtin_amdgcn_rcpf(1.0f + __builtin_amdgcn_exp2f(x * -1.44269504f));
}
// tanh(x) = 1 - 2/(1+2^(2x*log2e)); x->+inf: rcp(inf)=0 -> 1; x->-inf: rcp(1)=1 -> -1
__device__ __forceinline__ float tanh_hw(float x){
    return fmaf(-2.0f, __builtin_amdgcn_rcpf(1.0f + __builtin_amdgcn_exp2f(x * 2.88539008f)), 1.0f);
}

// ---------------- prep ----------------
__global__ void prep_kernel(const float* __restrict__ Wih_f, const float* __restrict__ Wih_b,
                            const float* __restrict__ Whh_f, const float* __restrict__ Whh_b,
                            const float* __restrict__ mlpW,
                            u16* __restrict__ WihF_p, u16* __restrict__ WihB_p,
                            u16* __restrict__ WhhF_p, u16* __restrict__ WhhB_p,
                            u16* __restrict__ mlpW_p,
                            float* __restrict__ bnSum, float* __restrict__ bnSumSq,
                            unsigned* __restrict__ pooled_u)
{
    const int tid  = blockIdx.x*blockDim.x + threadIdx.x;
    const int nthr = gridDim.x*blockDim.x;
    for (int i = tid; i < NG*EPAD; i += nthr){
        int g = i / EPAD, k = i % EPAD;
        WihF_p[i] = (k < NE) ? f2bf(Wih_f[g*NE + k]) : (u16)0;
        WihB_p[i] = (k < NE) ? f2bf(Wih_b[g*NE + k]) : (u16)0;
    }
    for (int i = tid; i < NG*NH; i += nthr){ WhhF_p[i] = f2bf(Whh_f[i]); WhhB_p[i] = f2bf(Whh_b[i]); }
    for (int i = tid; i < 512*512; i += nthr) mlpW_p[i] = f2bf(mlpW[i]);
    for (int i = tid; i < 512; i += nthr){ bnSum[i] = 0.0f; bnSumSq[i] = 0.0f; }
    for (int i = tid; i < NB*512; i += nthr) pooled_u[i] = 0u;
}

// ---------------- eproj: packed xprojP[row][col][{r,z,n,0}] bf16 ----------------
__global__ __launch_bounds__(512, 4)
void eproj_kernel(const int* __restrict__ x, const float* __restrict__ emb,
                  const u16* __restrict__ Wih_p, const float* __restrict__ b_ih,
                  const float* __restrict__ b_hh, u16* __restrict__ xprojP)
{
    __shared__ u16 a_lds[MRE*328];
    const int tid = threadIdx.x;
    const int mb  = blockIdx.x;       // 0..513
    {
        const int row = tid >> 4, jj = tid & 15;
        const int flat = mb*MRE + row;
        const int t_id = (flat < NCELL) ? x[flat] : 0;
        const float4* src = (const float4*)(emb + (size_t)t_id*NE);
        u16* dst = a_lds + row*328;
        for (int idx = jj; idx < 75; idx += 16){
            float4 v = src[idx];
            ushort4 o; o.x=f2bf(v.x); o.y=f2bf(v.y); o.z=f2bf(v.z); o.w=f2bf(v.w);
            *(ushort4*)(dst + idx*4) = o;
        }
        if (jj == 15){
            const ushort4 z = {0,0,0,0};
            #pragma unroll
            for (int c = 300; c < 320; c += 4) *(ushort4*)(dst + c) = z;
        }
    }
    __syncthreads();

    const int lane = tid & 63, wv = tid >> 6, l31 = lane & 31, q = lane >> 5;
    const int col = wv*32 + l31;
    f32x16 acc[3];
    #pragma unroll
    for (int g = 0; g < 3; g++)
        #pragma unroll
        for (int i = 0; i < 16; i++) acc[g][i] = 0.0f;

    const u16* a0p = a_lds + l31*328 + q*8;
    const u16* b0p = Wih_p + (size_t)(         col)*EPAD + q*8;
    const u16* b1p = Wih_p + (size_t)(NH     + col)*EPAD + q*8;
    const u16* b2p = Wih_p + (size_t)(2*NH   + col)*EPAD + q*8;

    #pragma unroll 4
    for (int kc = 0; kc < 20; kc++){
        const int ko = kc*16;
        bf16x8 a0 = *(const bf16x8*)(a0p + ko);
        bf16x8 b0 = *(const bf16x8*)(b0p + ko);
        bf16x8 b1 = *(const bf16x8*)(b1p + ko);
        bf16x8 b2 = *(const bf16x8*)(b2p + ko);
        acc[0] = MFMA32(a0,b0,acc[0],0,0,0);
        acc[1] = MFMA32(a0,b1,acc[1],0,0,0);
        acc[2] = MFMA32(a0,b2,acc[2],0,0,0);
    }
    const float br  = b_ih[col]      + b_hh[col];
    const float bz  = b_ih[NH+col]   + b_hh[NH+col];
    const float bn_ = b_ih[2*NH+col];
    #pragma unroll
    for (int r = 0; r < 16; r++){
        const int rit = (r&3) + 8*(r>>2) + 4*q;
        const int row = mb*MRE + rit;
        ushort4 o;
        o.x = f2bf(acc[0][r] + br);
        o.y = f2bf(acc[1][r] + bz);
        o.z = f2bf(acc[2][r] + bn_);
        o.w = 0;
        *(ushort4*)(xprojP + (size_t)row*1024 + col*4) = o;
    }
}

// ---------------- recurrence v7: 512-thr block, M=32 cells, 32x32x16 MFMA ----------------
// 8 waves x (32 cols x 3 gates), acc = 3 x f32x16; ~110 peak VGPR -> 2 independent blocks/CU
// (grid 512 = all resident). The two co-resident blocks have independent barriers, so one
// block's MFMA phase overlaps the other's gate-VALU/xproj-load phase (old 16-wave design
// was phase-lockstep). Gate math = hw v_exp/v_rcp (short chains); all 16 xg loads issued
// as one batch before the gate loop (single latency exposure per step).
__global__ __launch_bounds__(512, 4)
void recur_kernel(const int* __restrict__ x, const u16* __restrict__ xprojP,
                  const u16* __restrict__ Whh_p, const float* __restrict__ b_hh,
                  u16* __restrict__ hidden, float* __restrict__ bnSum, float* __restrict__ bnSumSq,
                  int dir)
{
    __shared__ u16 hb[2][32*HS];      // 2 x 32 x 264 u16 = 33.8 KB -> 2 blocks/CU fit
    __shared__ float maskv[32];
    const int tid = threadIdx.x;
    const int bid = blockIdx.x;       // 0..511
    const int mb  = ((bid & 7) << 6) | (bid >> 3);   // XCD -> contiguous 2048-row xproj slice
    if (tid < 32) maskv[tid] = (x[mb*32 + tid] > 0) ? 1.0f : 0.0f;
    __syncthreads();

    const int lane = tid & 63, wv = tid >> 6;        // wv 0..7
    const int l31 = lane & 31, q = lane >> 5;        // q 0..1
    const int col  = wv*32 + l31;                    // hidden column 0..255
    const int bidx = (mb*32) >> 9;
    const int s0   = (mb*32) & (NS-1);

    const float bhn = b_hh[2*NH + col];

    // W_hh planes as u32 byte offsets: row (g*256+col), k = kc*16 + q*8
    const char* whbase = (const char*)Whh_p;
    const u32 woff0 = (u32)(((         col)*NH + q*8) * 2);
    const u32 woff1 = (u32)(((NH     + col)*NH + q*8) * 2);
    const u32 woff2 = (u32)(((2*NH   + col)*NH + q*8) * 2);
    // xprojP: row*2048 + col*8 bytes
    const char* xbase = (const char*)xprojP;
    const u32 colByte = (u32)(col * 8);
    const u32 rowBase = (u32)(bidx * NS) * 2048u;
    const u32 padOff  = (u32)NCELL * 2048u + colByte;   // pad rows = token-0 projection

    // A-frag LDS offset: row l31, k = kc*16 + q*8  (row base l31*528 B is 16B-aligned)
    const int haOff = l31*HS + q*8;

    float hreg[16];
    #pragma unroll
    for (int i = 0; i < 16; i++) hreg[i] = 0.0f;

    #pragma unroll 1
    for (int t = 0; t < NW; t++){
        f32x16 acc0, acc1, acc2;
        #pragma unroll
        for (int i = 0; i < 16; i++){ acc0[i] = 0.0f; acc1[i] = 0.0f; acc2[i] = bhn; }

        if (t > 0){
            const u16* hcur = hb[t & 1] + haOff;
            // B pipelined one kc ahead of consumption
            bf16x8 b0 = *(const bf16x8*)(whbase + woff0);
            bf16x8 b1 = *(const bf16x8*)(whbase + woff1);
            bf16x8 b2 = *(const bf16x8*)(whbase + woff2);
            #pragma unroll
            for (int kc = 0; kc < 16; kc++){
                bf16x8 n0, n1, n2;
                if (kc < 15){
                    const int ko = (kc+1)*32;
                    n0 = *(const bf16x8*)(whbase + woff0 + ko);
                    n1 = *(const bf16x8*)(whbase + woff1 + ko);
                    n2 = *(const bf16x8*)(whbase + woff2 + ko);
                }
                bf16x8 a = *(const bf16x8*)(hcur + kc*16);
                acc0 = MFMA32(a, b0, acc0, 0,0,0);
                acc1 = MFMA32(a, b1, acc1, 0,0,0);
                acc2 = MFMA32(a, b2, acc2, 0,0,0);
                if (kc < 15){ b0 = n0; b1 = n1; b2 = n2; }
            }
        }
        // gate phase — all 16 xg loads batched (one latency exposure), hw-exp math
        const int sbase = s0 + ((dir == 0) ? (t - (NW-1)) : ((NW-1) - t));
        ushort4 xg[16];
        #pragma unroll
        for (int r = 0; r < 16; r++){
            const int rit = (r&3) + 8*(r>>2) + 4*q;       // 32x32 C-layout row
            const int j = sbase + rit;
            const u32 off = ((unsigned)j < (unsigned)NS) ? (rowBase + (u32)j*2048u + colByte) : padOff;
            xg[r] = *(const ushort4*)(xbase + off);
        }
        #pragma unroll
        for (int r = 0; r < 16; r++){
            const float xr = bf2f(xg[r].x), xz = bf2f(xg[r].y), xn = bf2f(xg[r].z);
            const float rg = sigm_hw(xr + acc0[r]);
            const float zg = sigm_hw(xz + acc1[r]);
            const float ng = tanh_hw(fmaf(rg, acc2[r], xn));
            hreg[r] = fmaf(zg, hreg[r] - ng, ng);
        }
        if (t + 1 < NW){
            u16* hw = hb[(t + 1) & 1];
            #pragma unroll
            for (int r = 0; r < 16; r++){
                const int rit = (r&3) + 8*(r>>2) + 4*q;
                hw[rit*HS + col] = f2bf_rh(hreg[r]);
            }
            __syncthreads();                 // single barrier per step (double buffer)
        }
    }
    // epilogue: mask, store hidden (bf16), BN partial sums
    float sum = 0.0f, sumsq = 0.0f;
    #pragma unroll
    for (int r = 0; r < 16; r++){
        const int rit = (r&3) + 8*(r>>2) + 4*q;
        const float hm = hreg[r] * maskv[rit];
        hidden[(size_t)(mb*32 + rit)*512 + dir*NH + col] = f2bf(hm);
        sum += hm; sumsq += hm*hm;
    }
    // lanes l31 and l31+32 share a col (q=0/1 cover rows 0..31 between them)
    sum += __shfl_xor(sum, 32);  sumsq += __shfl_xor(sumsq, 32);
    if (q == 0){
        atomicAdd(&bnSum[dir*NH + col], sum);
        atomicAdd(&bnSumSq[dir*NH + col], sumsq);
    }
}

// ---------------- BN finalize ----------------
__global__ void bnfin_kernel(const float* __restrict__ bnSum, const float* __restrict__ bnSumSq,
                             const float* __restrict__ gamma, const float* __restrict__ beta,
                             float* __restrict__ bnScale, float* __restrict__ bnShift)
{
    const int c = blockIdx.x*blockDim.x + threadIdx.x;
    if (c < 512){
        const float mu  = bnSum[c]   * (1.0f/16384.0f);
        const float var = bnSumSq[c] * (1.0f/16384.0f) - mu*mu;
        const float inv = rsqrtf(var + 1e-5f);
        const float sc  = gamma[c]*inv;
        bnScale[c] = sc;
        bnShift[c] = beta[c] - mu*sc;
    }
}

// ---------------- MLP + mask + max-pool ----------------
__global__ __launch_bounds__(512, 4)
void mlp_kernel(const int* __restrict__ x, const u16* __restrict__ hidden,
                const u16* __restrict__ mlpW_p, const float* __restrict__ bnScale,
                const float* __restrict__ bnShift, const float* __restrict__ mlp_b,
                unsigned* __restrict__ pooled_u)
{
    __shared__ u16 a_lds[MRE*520];
    __shared__ float maskv[MRE];
    const int tid = threadIdx.x;
    const int mb  = blockIdx.x;     // 0..511
    if (tid < MRE) maskv[tid] = (x[mb*MRE + tid] > 0) ? 1.0f : 0.0f;
    __syncthreads();
    {
        const int row = tid >> 4, jj = tid & 15;
        const float m = maskv[row];
        const u16* src = hidden + (size_t)(mb*MRE + row)*512;
        u16* dst = a_lds + row*520;
        for (int c4 = jj; c4 < 128; c4 += 16){
            ushort4 v = ((const ushort4*)src)[c4];
            const int c = c4*4;
            float4 sc = *(const float4*)(bnScale + c);
            float4 sh = *(const float4*)(bnShift + c);
            ushort4 o;
            o.x = f2bf((bf2f(v.x)*sc.x + sh.x)*m);
            o.y = f2bf((bf2f(v.y)*sc.y + sh.y)*m);
            o.z = f2bf((bf2f(v.z)*sc.z + sh.z)*m);
            o.w = f2bf((bf2f(v.w)*sc.w + sh.w)*m);
            *(ushort4*)(dst + c) = o;
        }
    }
    __syncthreads();

    const int lane = tid & 63, wv = tid >> 6, l31 = lane & 31, q = lane >> 5;
    f32x16 acc[2];
    #pragma unroll
    for (int g = 0; g < 2; g++)
        #pragma unroll
        for (int i = 0; i < 16; i++) acc[g][i] = 0.0f;

    const u16* a0p = a_lds + l31*520 + q*8;
    const u16* b0p = mlpW_p + (size_t)(wv*64 +      l31)*512 + q*8;
    const u16* b1p = mlpW_p + (size_t)(wv*64 + 32 + l31)*512 + q*8;

    #pragma unroll 4
    for (int kc = 0; kc < 32; kc++){
        const int ko = kc*16;
        bf16x8 a0 = *(const bf16x8*)(a0p + ko);
        bf16x8 b0 = *(const bf16x8*)(b0p + ko);
        bf16x8 b1 = *(const bf16x8*)(b1p + ko);
        acc[0] = MFMA32(a0,b0,acc[0],0,0,0);
        acc[1] = MFMA32(a0,b1,acc[1],0,0,0);
    }

    const int bidx = mb >> 4;
    #pragma unroll
    for (int nt = 0; nt < 2; nt++){
        const int colg = wv*64 + nt*32 + l31;
        const float bias = mlp_b[colg];
        float mx = -3.4e38f;
        #pragma unroll
        for (int r = 0; r < 16; r++){
            const int rit = (r&3) + 8*(r>>2) + 4*q;
            const float m = maskv[rit];
            const float v = (acc[nt][r] + bias)*m + (m - 1.0f)*65500.0f;
            mx = fmaxf(mx, v);
        }
        mx = fmaxf(mx, __shfl_xor(mx, 32));
        if (q == 0) atomicMax(&pooled_u[bidx*512 + colg], fkey(mx));
    }
}

// ---------------- final linear [32x512] @ [512x2] ----------------
__global__ void final_kernel(const unsigned* __restrict__ pooled_u,
                             const float* __restrict__ linW, const float* __restrict__ linb,
                             float* __restrict__ out)
{
    const int b = blockIdx.x;       // 32
    const int lane = threadIdx.x;   // 64
    float s0 = 0.0f, s1 = 0.0f;
    for (int c = lane; c < 512; c += 64){
        const unsigned u = pooled_u[b*512 + c];
        const unsigned bits = (u & 0x80000000u) ? (u ^ 0x80000000u) : ~u;
        const float f = __uint_as_float(bits);
        s0 += f * linW[c];
        s1 += f * linW[512 + c];
    }
    #pragma unroll
    for (int off = 32; off > 0; off >>= 1){
        s0 += __shfl_xor(s0, off);
        s1 += __shfl_xor(s1, off);
    }
    if (lane == 0){ out[2*b] = s0 + linb[0]; out[2*b + 1] = s1 + linb[1]; }
}

extern "C" void kernel_launch(void* const* d_in, const int* in_sizes, int n_in,
                              void* d_out, int out_size, void* d_ws, size_t ws_size,
                              hipStream_t stream)
{
    const int*   x     = (const int*)  d_in[0];
    const float* emb   = (const float*)d_in[5];
    const float* Wih_f = (const float*)d_in[6];
    const float* Whh_f = (const float*)d_in[7];
    const float* bih_f = (const float*)d_in[8];
    const float* bhh_f = (const float*)d_in[9];
    const float* Wih_b = (const float*)d_in[10];
    const float* Whh_b = (const float*)d_in[11];
    const float* bih_b = (const float*)d_in[12];
    const float* bhh_b = (const float*)d_in[13];
    const float* gamma = (const float*)d_in[14];
    const float* beta  = (const float*)d_in[15];
    const float* mlpW  = (const float*)d_in[16];
    const float* mlpb  = (const float*)d_in[17];
    const float* linW  = (const float*)d_in[18];
    const float* linb  = (const float*)d_in[19];
    float* out = (float*)d_out;
    char* ws = (char*)d_ws;

    u16*   WihF_p  = (u16*)  (ws + 0);
    u16*   WihB_p  = (u16*)  (ws + 491520);
    u16*   WhhF_p  = (u16*)  (ws + 983040);
    u16*   WhhB_p  = (u16*)  (ws + 1376256);
    u16*   mlpW_p  = (u16*)  (ws + 1769472);
    float* bnSum   = (float*)(ws + 2293760);
    float* bnSumSq = (float*)(ws + 2295808);
    float* bnScale = (float*)(ws + 2297856);
    float* bnShift = (float*)(ws + 2299904);
    unsigned* pooled_u = (unsigned*)(ws + 2301952);
    u16*   hidden  = (u16*)  (ws + 2367488);    // 16384x512 bf16
    u16*   xprojP  = (u16*)  (ws + 19144704);   // 16448x256x4 bf16 packed

    prep_kernel<<<512, 256, 0, stream>>>(Wih_f, Wih_b, Whh_f, Whh_b, mlpW,
                                         WihF_p, WihB_p, WhhF_p, WhhB_p, mlpW_p,
                                         bnSum, bnSumSq, pooled_u);
    // forward direction
    eproj_kernel<<<514, 512, 0, stream>>>(x, emb, WihF_p, bih_f, bhh_f, xprojP);
    recur_kernel<<<512, 512, 0, stream>>>(x, xprojP, WhhF_p, bhh_f, hidden, bnSum, bnSumSq, 0);
    // backward direction (reuses xprojP buffer)
    eproj_kernel<<<514, 512, 0, stream>>>(x, emb, WihB_p, bih_b, bhh_b, xprojP);
    recur_kernel<<<512, 512, 0, stream>>>(x, xprojP, WhhB_p, bhh_b, hidden, bnSum, bnSumSq, 1);

    bnfin_kernel<<<2, 256, 0, stream>>>(bnSum, bnSumSq, gamma, beta, bnScale, bnShift);
    mlp_kernel<<<512, 512, 0, stream>>>(x, hidden, mlpW_p, bnScale, bnShift, mlpb, pooled_u);
    final_kernel<<<32, 64, 0, stream>>>(pooled_u, linW, linb, out);
}

// Round 2
// 722.713 us; speedup vs baseline: 1.3245x; 1.3245x over previous
//
#include <hip/hip_runtime.h>
#include <hip/hip_bf16.h>
#include <stdint.h>

// DRNN_75204877353433: windowed bidirectional GRU (W=15) + BN + MLP + masked maxpool + linear
// B=32 S=512 W=15 E=300 H=256 V=50000 C=2, G=3H=768

typedef unsigned short u16;
typedef unsigned int u32;
typedef float f32x16 __attribute__((ext_vector_type(16)));
typedef float f32x4  __attribute__((ext_vector_type(4)));
typedef short bf16x8 __attribute__((ext_vector_type(8)));

#define MFMA32 __builtin_amdgcn_mfma_f32_32x32x16_bf16
#define MFMA16 __builtin_amdgcn_mfma_f32_16x16x32_bf16

#define NB 32
#define NS 512
#define NW 15
#define NE 300
#define NH 256
#define NG 768
#define NCELL (NB*NS)   // 16384
#define EPAD 320        // E padded to multiple of 16
#define MRE 32          // rows per block in eproj/mlp
#define MRR 64          // rows per block in recur (M=64 amortizes W_hh L2 traffic)
#define HS 264          // h_lds row stride (u16)

__device__ __forceinline__ float bf2f(u16 u){
    union { unsigned int i; float f; } v; v.i = ((unsigned int)u) << 16; return v.f;
}
__device__ __forceinline__ u16 f2bf(float f){
    union { float f; unsigned int i; } v; v.f = f;
    unsigned int x = v.i;
    x += 0x7fffu + ((x >> 16) & 1u);   // RNE
    return (u16)(x >> 16);
}
__device__ __forceinline__ u16 f2bf_rh(float f){   // round-half-up, 2 VALU ops
    return (u16)((__float_as_uint(f) + 0x8000u) >> 16);
}
__device__ __forceinline__ unsigned fkey(float f){   // order-preserving float->uint map
    unsigned b = __float_as_uint(f);
    return b ^ ((b & 0x80000000u) ? 0xFFFFFFFFu : 0x80000000u);
}

// ---- hw transcendental gate math (validated round 1): short chains, saturating edges ----
__device__ __forceinline__ float sigm_hw(float x){   // 1/(1+2^(-x*log2e))
    return __builtin_amdgcn_rcpf(1.0f + __builtin_amdgcn_exp2f(x * -1.44269504f));
}
__device__ __forceinline__ float tanh_hw(float x){   // 1 - 2/(1+2^(2x*log2e))
    return fmaf(-2.0f, __builtin_amdgcn_rcpf(1.0f + __builtin_amdgcn_exp2f(x * 2.88539008f)), 1.0f);
}

// ---------------- prep ----------------
// W_hh is packed into MFMA16 fragment order: per (gate g, wave wv, kc) a contiguous
// 1KB block, element addr = (((g*16+wv)*8+kc)*64 + lane)*16B. recur then loads it as
// base+lane*16 -> perfectly coalesced dwordx4 (the old row-gather touched ~32 cache
// lines per load instruction; that address serialization was the round-1 regression).
__global__ void prep_kernel(const float* __restrict__ Wih_f, const float* __restrict__ Wih_b,
                            const float* __restrict__ Whh_f, const float* __restrict__ Whh_b,
                            const float* __restrict__ mlpW,
                            u16* __restrict__ WihF_p, u16* __restrict__ WihB_p,
                            u16* __restrict__ WhhF_p, u16* __restrict__ WhhB_p,
                            u16* __restrict__ mlpW_p,
                            float* __restrict__ bnSum, float* __restrict__ bnSumSq,
                            unsigned* __restrict__ pooled_u)
{
    const int tid  = blockIdx.x*blockDim.x + threadIdx.x;
    const int nthr = gridDim.x*blockDim.x;
    for (int i = tid; i < NG*EPAD; i += nthr){
        int g = i / EPAD, k = i % EPAD;
        WihF_p[i] = (k < NE) ? f2bf(Wih_f[g*NE + k]) : (u16)0;
        WihB_p[i] = (k < NE) ? f2bf(Wih_b[g*NE + k]) : (u16)0;
    }
    // W_hh fragment pack: i = ((g*16+wv)*8+kc)*64 + lane, 8 u16 per i
    for (int i = tid; i < 3*16*8*64; i += nthr){
        const int lane = i & 63;
        const int kc   = (i >> 6) & 7;
        const int wvg  = i >> 9;           // g*16 + wv
        const int g    = wvg >> 4, wv = wvg & 15;
        const int l15  = lane & 15, q = lane >> 4;
        const int col  = wv*16 + l15;
        const int k0   = kc*32 + q*8;
        const float* srcF = Whh_f + (size_t)(g*NH + col)*NH + k0;
        const float* srcB = Whh_b + (size_t)(g*NH + col)*NH + k0;
        u16* dF = WhhF_p + (size_t)i*8;
        u16* dB = WhhB_p + (size_t)i*8;
        #pragma unroll
        for (int j = 0; j < 8; j++){ dF[j] = f2bf(srcF[j]); dB[j] = f2bf(srcB[j]); }
    }
    for (int i = tid; i < 512*512; i += nthr) mlpW_p[i] = f2bf(mlpW[i]);
    for (int i = tid; i < 512; i += nthr){ bnSum[i] = 0.0f; bnSumSq[i] = 0.0f; }
    for (int i = tid; i < NB*512; i += nthr) pooled_u[i] = 0u;
}

// ---------------- eproj: split xprojRZ (u32: r|z<<16) + xprojN (u16) ----------------
// 1536B/row total (vs 2048B padded before): per-XCD window slice = 3.1MB < 4MB L2,
// so the per-step re-read in recur stays L2-resident instead of thrashing to L3.
__global__ __launch_bounds__(512, 4)
void eproj_kernel(const int* __restrict__ x, const float* __restrict__ emb,
                  const u16* __restrict__ Wih_p, const float* __restrict__ b_ih,
                  const float* __restrict__ b_hh,
                  u32* __restrict__ xprojRZ, u16* __restrict__ xprojN)
{
    __shared__ u16 a_lds[MRE*328];
    const int tid = threadIdx.x;
    const int mb  = blockIdx.x;       // 0..513
    {
        const int row = tid >> 4, jj = tid & 15;
        const int flat = mb*MRE + row;
        const int t_id = (flat < NCELL) ? x[flat] : 0;
        const float4* src = (const float4*)(emb + (size_t)t_id*NE);
        u16* dst = a_lds + row*328;
        for (int idx = jj; idx < 75; idx += 16){
            float4 v = src[idx];
            ushort4 o; o.x=f2bf(v.x); o.y=f2bf(v.y); o.z=f2bf(v.z); o.w=f2bf(v.w);
            *(ushort4*)(dst + idx*4) = o;
        }
        if (jj == 15){
            const ushort4 z = {0,0,0,0};
            #pragma unroll
            for (int c = 300; c < 320; c += 4) *(ushort4*)(dst + c) = z;
        }
    }
    __syncthreads();

    const int lane = tid & 63, wv = tid >> 6, l31 = lane & 31, q = lane >> 5;
    const int col = wv*32 + l31;
    f32x16 acc[3];
    #pragma unroll
    for (int g = 0; g < 3; g++)
        #pragma unroll
        for (int i = 0; i < 16; i++) acc[g][i] = 0.0f;

    const u16* a0p = a_lds + l31*328 + q*8;
    const u16* b0p = Wih_p + (size_t)(         col)*EPAD + q*8;
    const u16* b1p = Wih_p + (size_t)(NH     + col)*EPAD + q*8;
    const u16* b2p = Wih_p + (size_t)(2*NH   + col)*EPAD + q*8;

    #pragma unroll 4
    for (int kc = 0; kc < 20; kc++){
        const int ko = kc*16;
        bf16x8 a0 = *(const bf16x8*)(a0p + ko);
        bf16x8 b0 = *(const bf16x8*)(b0p + ko);
        bf16x8 b1 = *(const bf16x8*)(b1p + ko);
        bf16x8 b2 = *(const bf16x8*)(b2p + ko);
        acc[0] = MFMA32(a0,b0,acc[0],0,0,0);
        acc[1] = MFMA32(a0,b1,acc[1],0,0,0);
        acc[2] = MFMA32(a0,b2,acc[2],0,0,0);
    }
    const float br  = b_ih[col]      + b_hh[col];
    const float bz  = b_ih[NH+col]   + b_hh[NH+col];
    const float bn_ = b_ih[2*NH+col];
    #pragma unroll
    for (int r = 0; r < 16; r++){
        const int rit = (r&3) + 8*(r>>2) + 4*q;
        const int row = mb*MRE + rit;
        const u32 rzv = (u32)f2bf(acc[0][r] + br) | ((u32)f2bf(acc[1][r] + bz) << 16);
        xprojRZ[(size_t)row*256 + col] = rzv;
        xprojN [(size_t)row*256 + col] = f2bf(acc[2][r] + bn_);
    }
}

// ---------------- recurrence v8: M=64, 16 waves, MFMA16 (round-0 structure) ----------------
// + fragment-packed coalesced W_hh loads, + L2-resident split xproj, + hw gate math,
// + all 32 gate loads batched into one latency exposure per step.
__global__ __launch_bounds__(1024, 4)
void recur_kernel(const int* __restrict__ x,
                  const u32* __restrict__ xprojRZ, const u16* __restrict__ xprojN,
                  const u16* __restrict__ Whh_p, const float* __restrict__ b_hh,
                  u16* __restrict__ hidden, float* __restrict__ bnSum, float* __restrict__ bnSumSq,
                  int dir)
{
    __shared__ u16 hb[2][MRR*HS];     // 2 x 64 x 264 u16 = 67.5 KB
    __shared__ float maskv[MRR];
    const int tid = threadIdx.x;
    const int bid = blockIdx.x;       // 0..255
    const int mb  = ((bid & 7) << 5) | (bid >> 3);   // XCD -> contiguous 2048-row xproj slice
    if (tid < MRR) maskv[tid] = (x[mb*MRR + tid] > 0) ? 1.0f : 0.0f;
    __syncthreads();

    const int lane = tid & 63, wv = tid >> 6;        // wv 0..15
    const int l15 = lane & 15, q = lane >> 4;        // q 0..3
    const int col  = wv*16 + l15;                    // hidden column 0..255
    const int bidx = (mb*MRR) >> 9;
    const int s0   = (mb*MRR) & (NS-1);

    const float bhn = b_hh[2*NH + col];

    // fragment-packed W_hh: wave's stream base, gate at +g*131072, kc at +kc*1024
    const char* wf = (const char*)Whh_p + ((size_t)wv << 13) + ((size_t)lane << 4);

    // split xproj byte bases
    const char* xrzb = (const char*)xprojRZ;
    const char* xnb  = (const char*)xprojN;
    const u32 colRZ = (u32)(col * 4);
    const u32 colN  = (u32)(col * 2);
    const u32 rowBaseRZ = (u32)(bidx * NS) * 1024u;
    const u32 rowBaseN  = (u32)(bidx * NS) * 512u;
    const u32 padRZ = (u32)NCELL * 1024u + colRZ;    // pad row = token-0 projection
    const u32 padN  = (u32)NCELL * 512u  + colN;

    // A-frag LDS offset: row (mt*16 + l15), k = kc*32 + q*8
    const int haOff = l15*HS + q*8;

    float hreg[16];
    #pragma unroll
    for (int i = 0; i < 16; i++) hreg[i] = 0.0f;

    #pragma unroll 1
    for (int t = 0; t < NW; t++){
        f32x4 acc[4][3];
        #pragma unroll
        for (int mt = 0; mt < 4; mt++)
            #pragma unroll
            for (int g = 0; g < 3; g++)
                #pragma unroll
                for (int i = 0; i < 4; i++) acc[mt][g][i] = (g == 2) ? bhn : 0.0f;

        if (t > 0){
            const u16* hcur = hb[t & 1] + haOff;
            // B pipelined one kc ahead of consumption (coalesced fragment loads)
            bf16x8 b0 = *(const bf16x8*)(wf + 0*131072);
            bf16x8 b1 = *(const bf16x8*)(wf + 1*131072);
            bf16x8 b2 = *(const bf16x8*)(wf + 2*131072);
            #pragma unroll
            for (int kc = 0; kc < 8; kc++){
                bf16x8 n0, n1, n2;
                if (kc < 7){
                    const int ko = (kc+1)*1024;
                    n0 = *(const bf16x8*)(wf + 0*131072 + ko);
                    n1 = *(const bf16x8*)(wf + 1*131072 + ko);
                    n2 = *(const bf16x8*)(wf + 2*131072 + ko);
                }
                bf16x8 a0 = *(const bf16x8*)(hcur + kc*32 +   0);
                bf16x8 a1 = *(const bf16x8*)(hcur + kc*32 + 16*HS);
                bf16x8 a2 = *(const bf16x8*)(hcur + kc*32 + 32*HS);
                bf16x8 a3 = *(const bf16x8*)(hcur + kc*32 + 48*HS);
                acc[0][0] = MFMA16(a0,b0,acc[0][0],0,0,0);
                acc[1][0] = MFMA16(a1,b0,acc[1][0],0,0,0);
                acc[2][0] = MFMA16(a2,b0,acc[2][0],0,0,0);
                acc[3][0] = MFMA16(a3,b0,acc[3][0],0,0,0);
                acc[0][1] = MFMA16(a0,b1,acc[0][1],0,0,0);
                acc[1][1] = MFMA16(a1,b1,acc[1][1],0,0,0);
                acc[2][1] = MFMA16(a2,b1,acc[2][1],0,0,0);
                acc[3][1] = MFMA16(a3,b1,acc[3][1],0,0,0);
                acc[0][2] = MFMA16(a0,b2,acc[0][2],0,0,0);
                acc[1][2] = MFMA16(a1,b2,acc[1][2],0,0,0);
                acc[2][2] = MFMA16(a2,b2,acc[2][2],0,0,0);
                acc[3][2] = MFMA16(a3,b2,acc[3][2],0,0,0);
                if (kc < 7){ b0 = n0; b1 = n1; b2 = n2; }
            }
        }
        // gate phase — all 32 loads batched (single latency exposure), hw-exp math
        const int sbase = s0 + ((dir == 0) ? (t - (NW-1)) : ((NW-1) - t));
        u32 rz[16]; u16 nn[16];
        #pragma unroll
        for (int i = 0; i < 16; i++){
            const int mt = i >> 2, r = i & 3;
            const int rit = mt*16 + q*4 + r;
            const int j = sbase + rit;
            const bool inb = ((unsigned)j < (unsigned)NS);
            const u32 offRZ = inb ? (rowBaseRZ + (u32)j*1024u + colRZ) : padRZ;
            const u32 offN  = inb ? (rowBaseN  + (u32)j*512u  + colN ) : padN;
            rz[i] = *(const u32*)(xrzb + offRZ);
            nn[i] = *(const u16*)(xnb + offN);
        }
        #pragma unroll
        for (int i = 0; i < 16; i++){
            const int mt = i >> 2, r = i & 3;
            const float xr = bf2f((u16)(rz[i] & 0xFFFFu));
            const float xz = bf2f((u16)(rz[i] >> 16));
            const float xn = bf2f(nn[i]);
            const float rg = sigm_hw(xr + acc[mt][0][r]);
            const float zg = sigm_hw(xz + acc[mt][1][r]);
            const float ng = tanh_hw(fmaf(rg, acc[mt][2][r], xn));
            hreg[i] = fmaf(zg, hreg[i] - ng, ng);
        }
        if (t + 1 < NW){
            u16* hw = hb[(t + 1) & 1];
            #pragma unroll
            for (int mt = 0; mt < 4; mt++)
                #pragma unroll
                for (int r = 0; r < 4; r++){
                    const int rit = mt*16 + q*4 + r;
                    hw[rit*HS + col] = f2bf_rh(hreg[mt*4 + r]);
                }
            __syncthreads();                 // single barrier per step (double buffer)
        }
    }
    // epilogue: mask, store hidden (bf16), BN partial sums
    float sum = 0.0f, sumsq = 0.0f;
    #pragma unroll
    for (int mt = 0; mt < 4; mt++)
        #pragma unroll
        for (int r = 0; r < 4; r++){
            const int rit = mt*16 + q*4 + r;
            const float hm = hreg[mt*4 + r] * maskv[rit];
            hidden[(size_t)(mb*MRR + rit)*512 + dir*NH + col] = f2bf(hm);
            sum += hm; sumsq += hm*hm;
        }
    // reduce across q (lanes l15, l15+16, l15+32, l15+48 share a col)
    sum   += __shfl_xor(sum, 16);   sumsq += __shfl_xor(sumsq, 16);
    sum   += __shfl_xor(sum, 32);   sumsq += __shfl_xor(sumsq, 32);
    if (q == 0){
        atomicAdd(&bnSum[dir*NH + col], sum);
        atomicAdd(&bnSumSq[dir*NH + col], sumsq);
    }
}

// ---------------- BN finalize ----------------
__global__ void bnfin_kernel(const float* __restrict__ bnSum, const float* __restrict__ bnSumSq,
                             const float* __restrict__ gamma, const float* __restrict__ beta,
                             float* __restrict__ bnScale, float* __restrict__ bnShift)
{
    const int c = blockIdx.x*blockDim.x + threadIdx.x;
    if (c < 512){
        const float mu  = bnSum[c]   * (1.0f/16384.0f);
        const float var = bnSumSq[c] * (1.0f/16384.0f) - mu*mu;
        const float inv = rsqrtf(var + 1e-5f);
        const float sc  = gamma[c]*inv;
        bnScale[c] = sc;
        bnShift[c] = beta[c] - mu*sc;
    }
}

// ---------------- MLP + mask + max-pool ----------------
__global__ __launch_bounds__(512, 4)
void mlp_kernel(const int* __restrict__ x, const u16* __restrict__ hidden,
                const u16* __restrict__ mlpW_p, const float* __restrict__ bnScale,
                const float* __restrict__ bnShift, const float* __restrict__ mlp_b,
                unsigned* __restrict__ pooled_u)
{
    __shared__ u16 a_lds[MRE*520];
    __shared__ float maskv[MRE];
    const int tid = threadIdx.x;
    const int mb  = blockIdx.x;     // 0..511
    if (tid < MRE) maskv[tid] = (x[mb*MRE + tid] > 0) ? 1.0f : 0.0f;
    __syncthreads();
    {
        const int row = tid >> 4, jj = tid & 15;
        const float m = maskv[row];
        const u16* src = hidden + (size_t)(mb*MRE + row)*512;
        u16* dst = a_lds + row*520;
        for (int c4 = jj; c4 < 128; c4 += 16){
            ushort4 v = ((const ushort4*)src)[c4];
            const int c = c4*4;
            float4 sc = *(const float4*)(bnScale + c);
            float4 sh = *(const float4*)(bnShift + c);
            ushort4 o;
            o.x = f2bf((bf2f(v.x)*sc.x + sh.x)*m);
            o.y = f2bf((bf2f(v.y)*sc.y + sh.y)*m);
            o.z = f2bf((bf2f(v.z)*sc.z + sh.z)*m);
            o.w = f2bf((bf2f(v.w)*sc.w + sh.w)*m);
            *(ushort4*)(dst + c) = o;
        }
    }
    __syncthreads();

    const int lane = tid & 63, wv = tid >> 6, l31 = lane & 31, q = lane >> 5;
    f32x16 acc[2];
    #pragma unroll
    for (int g = 0; g < 2; g++)
        #pragma unroll
        for (int i = 0; i < 16; i++) acc[g][i] = 0.0f;

    const u16* a0p = a_lds + l31*520 + q*8;
    const u16* b0p = mlpW_p + (size_t)(wv*64 +      l31)*512 + q*8;
    const u16* b1p = mlpW_p + (size_t)(wv*64 + 32 + l31)*512 + q*8;

    #pragma unroll 4
    for (int kc = 0; kc < 32; kc++){
        const int ko = kc*16;
        bf16x8 a0 = *(const bf16x8*)(a0p + ko);
        bf16x8 b0 = *(const bf16x8*)(b0p + ko);
        bf16x8 b1 = *(const bf16x8*)(b1p + ko);
        acc[0] = MFMA32(a0,b0,acc[0],0,0,0);
        acc[1] = MFMA32(a0,b1,acc[1],0,0,0);
    }

    const int bidx = mb >> 4;
    #pragma unroll
    for (int nt = 0; nt < 2; nt++){
        const int colg = wv*64 + nt*32 + l31;
        const float bias = mlp_b[colg];
        float mx = -3.4e38f;
        #pragma unroll
        for (int r = 0; r < 16; r++){
            const int rit = (r&3) + 8*(r>>2) + 4*q;
            const float m = maskv[rit];
            const float v = (acc[nt][r] + bias)*m + (m - 1.0f)*65500.0f;
            mx = fmaxf(mx, v);
        }
        mx = fmaxf(mx, __shfl_xor(mx, 32));
        if (q == 0) atomicMax(&pooled_u[bidx*512 + colg], fkey(mx));
    }
}

// ---------------- final linear [32x512] @ [512x2] ----------------
__global__ void final_kernel(const unsigned* __restrict__ pooled_u,
                             const float* __restrict__ linW, const float* __restrict__ linb,
                             float* __restrict__ out)
{
    const int b = blockIdx.x;       // 32
    const int lane = threadIdx.x;   // 64
    float s0 = 0.0f, s1 = 0.0f;
    for (int c = lane; c < 512; c += 64){
        const unsigned u = pooled_u[b*512 + c];
        const unsigned bits = (u & 0x80000000u) ? (u ^ 0x80000000u) : ~u;
        const float f = __uint_as_float(bits);
        s0 += f * linW[c];
        s1 += f * linW[512 + c];
    }
    #pragma unroll
    for (int off = 32; off > 0; off >>= 1){
        s0 += __shfl_xor(s0, off);
        s1 += __shfl_xor(s1, off);
    }
    if (lane == 0){ out[2*b] = s0 + linb[0]; out[2*b + 1] = s1 + linb[1]; }
}

extern "C" void kernel_launch(void* const* d_in, const int* in_sizes, int n_in,
                              void* d_out, int out_size, void* d_ws, size_t ws_size,
                              hipStream_t stream)
{
    const int*   x     = (const int*)  d_in[0];
    const float* emb   = (const float*)d_in[5];
    const float* Wih_f = (const float*)d_in[6];
    const float* Whh_f = (const float*)d_in[7];
    const float* bih_f = (const float*)d_in[8];
    const float* bhh_f = (const float*)d_in[9];
    const float* Wih_b = (const float*)d_in[10];
    const float* Whh_b = (const float*)d_in[11];
    const float* bih_b = (const float*)d_in[12];
    const float* bhh_b = (const float*)d_in[13];
    const float* gamma = (const float*)d_in[14];
    const float* beta  = (const float*)d_in[15];
    const float* mlpW  = (const float*)d_in[16];
    const float* mlpb  = (const float*)d_in[17];
    const float* linW  = (const float*)d_in[18];
    const float* linb  = (const float*)d_in[19];
    float* out = (float*)d_out;
    char* ws = (char*)d_ws;

    u16*   WihF_p  = (u16*)  (ws + 0);
    u16*   WihB_p  = (u16*)  (ws + 491520);
    u16*   WhhF_p  = (u16*)  (ws + 983040);      // fragment-packed, 393216 B
    u16*   WhhB_p  = (u16*)  (ws + 1376256);
    u16*   mlpW_p  = (u16*)  (ws + 1769472);
    float* bnSum   = (float*)(ws + 2293760);
    float* bnSumSq = (float*)(ws + 2295808);
    float* bnScale = (float*)(ws + 2297856);
    float* bnShift = (float*)(ws + 2299904);
    unsigned* pooled_u = (unsigned*)(ws + 2301952);
    u16*   hidden  = (u16*)  (ws + 2367488);     // 16384x512 bf16
    u32*   xprojRZ = (u32*)  (ws + 19144704);    // 16448x256 u32 (r|z<<16), 16842752 B
    u16*   xprojN  = (u16*)  (ws + 35987456);    // 16448x256 u16, 8421376 B

    prep_kernel<<<512, 256, 0, stream>>>(Wih_f, Wih_b, Whh_f, Whh_b, mlpW,
                                         WihF_p, WihB_p, WhhF_p, WhhB_p, mlpW_p,
                                         bnSum, bnSumSq, pooled_u);
    // forward direction
    eproj_kernel<<<514, 512, 0, stream>>>(x, emb, WihF_p, bih_f, bhh_f, xprojRZ, xprojN);
    recur_kernel<<<256, 1024, 0, stream>>>(x, xprojRZ, xprojN, WhhF_p, bhh_f, hidden, bnSum, bnSumSq, 0);
    // backward direction (reuses xproj buffers)
    eproj_kernel<<<514, 512, 0, stream>>>(x, emb, WihB_p, bih_b, bhh_b, xprojRZ, xprojN);
    recur_kernel<<<256, 1024, 0, stream>>>(x, xprojRZ, xprojN, WhhB_p, bhh_b, hidden, bnSum, bnSumSq, 1);

    bnfin_kernel<<<2, 256, 0, stream>>>(bnSum, bnSumSq, gamma, beta, bnScale, bnShift);
    mlp_kernel<<<512, 512, 0, stream>>>(x, hidden, mlpW_p, bnScale, bnShift, mlpb, pooled_u);
    final_kernel<<<32, 64, 0, stream>>>(pooled_u, linW, linb, out);
}

// Round 3
// 600.975 us; speedup vs baseline: 1.5927x; 1.2026x over previous
//
#include <hip/hip_runtime.h>
#include <hip/hip_bf16.h>
#include <stdint.h>

// DRNN_75204877353433: windowed bidirectional GRU (W=15) + BN + MLP + masked maxpool + linear
// B=32 S=512 W=15 E=300 H=256 V=50000 C=2, G=3H=768

typedef unsigned short u16;
typedef unsigned int u32;
typedef float f32x16 __attribute__((ext_vector_type(16)));
typedef float f32x4  __attribute__((ext_vector_type(4)));
typedef short bf16x8 __attribute__((ext_vector_type(8)));

#define MFMA32 __builtin_amdgcn_mfma_f32_32x32x16_bf16
#define MFMA16 __builtin_amdgcn_mfma_f32_16x16x32_bf16

#define NB 32
#define NS 512
#define NW 15
#define NE 300
#define NH 256
#define NG 768
#define NCELL (NB*NS)   // 16384
#define EPAD 320        // E padded to multiple of 16
#define MRE 32          // rows per block in eproj/mlp
#define MRR 64          // rows per block in recur
#define HS 264          // h_lds row stride (u16)
#define WROWS 78        // xproj window rows per block (64 + 14)
#define RZS 260         // rz_lds row stride (u32): 4*4*260 mod 128B -> q-groups split banks
#define NSS 264         // n_lds row stride (u16)

__device__ __forceinline__ float bf2f(u16 u){
    union { unsigned int i; float f; } v; v.i = ((unsigned int)u) << 16; return v.f;
}
__device__ __forceinline__ u16 f2bf(float f){
    union { float f; unsigned int i; } v; v.f = f;
    unsigned int x = v.i;
    x += 0x7fffu + ((x >> 16) & 1u);   // RNE
    return (u16)(x >> 16);
}
__device__ __forceinline__ u16 f2bf_rh(float f){   // round-half-up, 2 VALU ops
    return (u16)((__float_as_uint(f) + 0x8000u) >> 16);
}
__device__ __forceinline__ unsigned fkey(float f){   // order-preserving float->uint map
    unsigned b = __float_as_uint(f);
    return b ^ ((b & 0x80000000u) ? 0xFFFFFFFFu : 0x80000000u);
}

// ---- hw transcendental gate math (validated round 1): short chains, saturating edges ----
__device__ __forceinline__ float sigm_hw(float x){   // 1/(1+2^(-x*log2e))
    return __builtin_amdgcn_rcpf(1.0f + __builtin_amdgcn_exp2f(x * -1.44269504f));
}
__device__ __forceinline__ float tanh_hw(float x){   // 1 - 2/(1+2^(2x*log2e))
    return fmaf(-2.0f, __builtin_amdgcn_rcpf(1.0f + __builtin_amdgcn_exp2f(x * 2.88539008f)), 1.0f);
}

// ---------------- prep ----------------
// W_hh packed into MFMA16 fragment order: per (gate g, wave wv, kc) a contiguous
// 1KB block, element addr = (((g*16+wv)*8+kc)*64 + lane)*16B -> recur loads are
// base+lane*16, perfectly coalesced dwordx4 (round-1's row-gather was the regression).
__global__ void prep_kernel(const float* __restrict__ Wih_f, const float* __restrict__ Wih_b,
                            const float* __restrict__ Whh_f, const float* __restrict__ Whh_b,
                            const float* __restrict__ mlpW,
                            u16* __restrict__ WihF_p, u16* __restrict__ WihB_p,
                            u16* __restrict__ WhhF_p, u16* __restrict__ WhhB_p,
                            u16* __restrict__ mlpW_p,
                            float* __restrict__ bnSum, float* __restrict__ bnSumSq,
                            unsigned* __restrict__ pooled_u)
{
    const int tid  = blockIdx.x*blockDim.x + threadIdx.x;
    const int nthr = gridDim.x*blockDim.x;
    for (int i = tid; i < NG*EPAD; i += nthr){
        int g = i / EPAD, k = i % EPAD;
        WihF_p[i] = (k < NE) ? f2bf(Wih_f[g*NE + k]) : (u16)0;
        WihB_p[i] = (k < NE) ? f2bf(Wih_b[g*NE + k]) : (u16)0;
    }
    // W_hh fragment pack: i = ((g*16+wv)*8+kc)*64 + lane, 8 u16 per i
    for (int i = tid; i < 3*16*8*64; i += nthr){
        const int lane = i & 63;
        const int kc   = (i >> 6) & 7;
        const int wvg  = i >> 9;           // g*16 + wv
        const int g    = wvg >> 4, wv = wvg & 15;
        const int l15  = lane & 15, q = lane >> 4;
        const int col  = wv*16 + l15;
        const int k0   = kc*32 + q*8;
        const float* srcF = Whh_f + (size_t)(g*NH + col)*NH + k0;
        const float* srcB = Whh_b + (size_t)(g*NH + col)*NH + k0;
        u16* dF = WhhF_p + (size_t)i*8;
        u16* dB = WhhB_p + (size_t)i*8;
        #pragma unroll
        for (int j = 0; j < 8; j++){ dF[j] = f2bf(srcF[j]); dB[j] = f2bf(srcB[j]); }
    }
    for (int i = tid; i < 512*512; i += nthr) mlpW_p[i] = f2bf(mlpW[i]);
    for (int i = tid; i < 512; i += nthr){ bnSum[i] = 0.0f; bnSumSq[i] = 0.0f; }
    for (int i = tid; i < NB*512; i += nthr) pooled_u[i] = 0u;
}

// ---------------- eproj: split xprojRZ (u32: r|z<<16) + xprojN (u16) ----------------
__global__ __launch_bounds__(512, 4)
void eproj_kernel(const int* __restrict__ x, const float* __restrict__ emb,
                  const u16* __restrict__ Wih_p, const float* __restrict__ b_ih,
                  const float* __restrict__ b_hh,
                  u32* __restrict__ xprojRZ, u16* __restrict__ xprojN)
{
    __shared__ u16 a_lds[MRE*328];
    const int tid = threadIdx.x;
    const int mb  = blockIdx.x;       // 0..513
    {
        const int row = tid >> 4, jj = tid & 15;
        const int flat = mb*MRE + row;
        const int t_id = (flat < NCELL) ? x[flat] : 0;
        const float4* src = (const float4*)(emb + (size_t)t_id*NE);
        u16* dst = a_lds + row*328;
        for (int idx = jj; idx < 75; idx += 16){
            float4 v = src[idx];
            ushort4 o; o.x=f2bf(v.x); o.y=f2bf(v.y); o.z=f2bf(v.z); o.w=f2bf(v.w);
            *(ushort4*)(dst + idx*4) = o;
        }
        if (jj == 15){
            const ushort4 z = {0,0,0,0};
            #pragma unroll
            for (int c = 300; c < 320; c += 4) *(ushort4*)(dst + c) = z;
        }
    }
    __syncthreads();

    const int lane = tid & 63, wv = tid >> 6, l31 = lane & 31, q = lane >> 5;
    const int col = wv*32 + l31;
    f32x16 acc[3];
    #pragma unroll
    for (int g = 0; g < 3; g++)
        #pragma unroll
        for (int i = 0; i < 16; i++) acc[g][i] = 0.0f;

    const u16* a0p = a_lds + l31*328 + q*8;
    const u16* b0p = Wih_p + (size_t)(         col)*EPAD + q*8;
    const u16* b1p = Wih_p + (size_t)(NH     + col)*EPAD + q*8;
    const u16* b2p = Wih_p + (size_t)(2*NH   + col)*EPAD + q*8;

    #pragma unroll 4
    for (int kc = 0; kc < 20; kc++){
        const int ko = kc*16;
        bf16x8 a0 = *(const bf16x8*)(a0p + ko);
        bf16x8 b0 = *(const bf16x8*)(b0p + ko);
        bf16x8 b1 = *(const bf16x8*)(b1p + ko);
        bf16x8 b2 = *(const bf16x8*)(b2p + ko);
        acc[0] = MFMA32(a0,b0,acc[0],0,0,0);
        acc[1] = MFMA32(a0,b1,acc[1],0,0,0);
        acc[2] = MFMA32(a0,b2,acc[2],0,0,0);
    }
    const float br  = b_ih[col]      + b_hh[col];
    const float bz  = b_ih[NH+col]   + b_hh[NH+col];
    const float bn_ = b_ih[2*NH+col];
    #pragma unroll
    for (int r = 0; r < 16; r++){
        const int rit = (r&3) + 8*(r>>2) + 4*q;
        const int row = mb*MRE + rit;
        const u32 rzv = (u32)f2bf(acc[0][r] + br) | ((u32)f2bf(acc[1][r] + bz) << 16);
        xprojRZ[(size_t)row*256 + col] = rzv;
        xprojN [(size_t)row*256 + col] = f2bf(acc[2][r] + bn_);
    }
}

// ---------------- recurrence v9: LDS-resident xproj window ----------------
// Round-2 PMC: FETCH 434MB == full no-reuse window traffic (377MB) + Whh conflict
// misses -> the recurrence was HBM-bound on per-step xproj re-reads at 2 TB/s.
// Fix: each block's 15 steps touch exactly 78 xproj rows (64-cell tile slides 1/step);
// stage them in LDS ONCE (coalesced, each row fetched exactly once), single-buffer h
// (2 barriers/step) to fit: 81120(RZ) + 41184(N) + 33792(h) + 256(mask) = 156352 B.
// Gate loads become immediate-offset ds_read; bounds-clamp moves to staging.
__global__ __launch_bounds__(1024, 4)
void recur_kernel(const int* __restrict__ x,
                  const u32* __restrict__ xprojRZ, const u16* __restrict__ xprojN,
                  const u16* __restrict__ Whh_p, const float* __restrict__ b_hh,
                  u16* __restrict__ hidden, float* __restrict__ bnSum, float* __restrict__ bnSumSq,
                  int dir)
{
    __shared__ u32 rz_lds[WROWS*RZS];   // 81120 B
    __shared__ u16 n_lds [WROWS*NSS];   // 41184 B
    __shared__ u16 h_lds [MRR*HS];      // 33792 B
    __shared__ float maskv[MRR];
    const int tid = threadIdx.x;
    const int bid = blockIdx.x;       // 0..255
    const int mb  = ((bid & 7) << 5) | (bid >> 3);   // XCD -> contiguous 2048-row xproj slice
    if (tid < MRR) maskv[tid] = (x[mb*MRR + tid] > 0) ? 1.0f : 0.0f;

    const int bidx = (mb*MRR) >> 9;
    const int s0   = (mb*MRR) & (NS-1);
    const int joff = s0 + (dir ? 0 : -(NW-1));       // window row w -> seq index j = joff + w

    // ---- stage the 78-row window (clamped rows -> pad row NCELL = token-0 projection) ----
    for (int i = tid; i < WROWS*64; i += 1024){
        const int w = i >> 6, c4 = i & 63;
        const int j = joff + w;
        const size_t row = ((unsigned)j < (unsigned)NS) ? (size_t)(bidx*NS + j) : (size_t)NCELL;
        const uint4 v = *(const uint4*)(xprojRZ + row*256 + c4*4);
        *(uint4*)(rz_lds + w*RZS + c4*4) = v;
    }
    for (int i = tid; i < WROWS*32; i += 1024){
        const int w = i >> 5, c8 = i & 31;
        const int j = joff + w;
        const size_t row = ((unsigned)j < (unsigned)NS) ? (size_t)(bidx*NS + j) : (size_t)NCELL;
        const uint4 v = *(const uint4*)(xprojN + row*256 + c8*8);
        *(uint4*)(n_lds + w*NSS + c8*8) = v;
    }
    __syncthreads();

    const int lane = tid & 63, wv = tid >> 6;        // wv 0..15
    const int l15 = lane & 15, q = lane >> 4;        // q 0..3
    const int col  = wv*16 + l15;                    // hidden column 0..255

    const float bhn = b_hh[2*NH + col];

    // fragment-packed W_hh: wave's stream base, gate at +g*131072, kc at +kc*1024
    const char* wf = (const char*)Whh_p + ((size_t)wv << 13) + ((size_t)lane << 4);

    // A-frag LDS offset: row (mt*16 + l15), k = kc*32 + q*8
    const int haOff = l15*HS + q*8;
    // gate-read dynamic bases (per-thread); (mt*16+r)*stride fits DS imm offset
    const u32* rzp0 = rz_lds + q*4*RZS + col;
    const u16* nnp0 = n_lds  + q*4*NSS + col;

    float hreg[16];
    #pragma unroll
    for (int i = 0; i < 16; i++) hreg[i] = 0.0f;

    #pragma unroll 1
    for (int t = 0; t < NW; t++){
        f32x4 acc[4][3];
        #pragma unroll
        for (int mt = 0; mt < 4; mt++)
            #pragma unroll
            for (int g = 0; g < 3; g++)
                #pragma unroll
                for (int i = 0; i < 4; i++) acc[mt][g][i] = (g == 2) ? bhn : 0.0f;

        if (t > 0){
            const u16* hcur = h_lds + haOff;
            // B pipelined one kc ahead of consumption (coalesced fragment loads, L2-hot)
            bf16x8 b0 = *(const bf16x8*)(wf + 0*131072);
            bf16x8 b1 = *(const bf16x8*)(wf + 1*131072);
            bf16x8 b2 = *(const bf16x8*)(wf + 2*131072);
            #pragma unroll
            for (int kc = 0; kc < 8; kc++){
                bf16x8 n0, n1, n2;
                if (kc < 7){
                    const int ko = (kc+1)*1024;
                    n0 = *(const bf16x8*)(wf + 0*131072 + ko);
                    n1 = *(const bf16x8*)(wf + 1*131072 + ko);
                    n2 = *(const bf16x8*)(wf + 2*131072 + ko);
                }
                bf16x8 a0 = *(const bf16x8*)(hcur + kc*32 +   0);
                bf16x8 a1 = *(const bf16x8*)(hcur + kc*32 + 16*HS);
                bf16x8 a2 = *(const bf16x8*)(hcur + kc*32 + 32*HS);
                bf16x8 a3 = *(const bf16x8*)(hcur + kc*32 + 48*HS);
                acc[0][0] = MFMA16(a0,b0,acc[0][0],0,0,0);
                acc[1][0] = MFMA16(a1,b0,acc[1][0],0,0,0);
                acc[2][0] = MFMA16(a2,b0,acc[2][0],0,0,0);
                acc[3][0] = MFMA16(a3,b0,acc[3][0],0,0,0);
                acc[0][1] = MFMA16(a0,b1,acc[0][1],0,0,0);
                acc[1][1] = MFMA16(a1,b1,acc[1][1],0,0,0);
                acc[2][1] = MFMA16(a2,b1,acc[2][1],0,0,0);
                acc[3][1] = MFMA16(a3,b1,acc[3][1],0,0,0);
                acc[0][2] = MFMA16(a0,b2,acc[0][2],0,0,0);
                acc[1][2] = MFMA16(a1,b2,acc[1][2],0,0,0);
                acc[2][2] = MFMA16(a2,b2,acc[2][2],0,0,0);
                acc[3][2] = MFMA16(a3,b2,acc[3][2],0,0,0);
                if (kc < 7){ b0 = n0; b1 = n1; b2 = n2; }
            }
        }
        // gate phase — window reads from LDS (immediate-offset ds_read), hw-exp math
        const int wbase = (dir == 0) ? t : ((NW-1) - t);
        const u32* rzp = rzp0 + wbase*RZS;
        const u16* nnp = nnp0 + wbase*NSS;
        u32 rz[16]; u16 nn[16];
        #pragma unroll
        for (int i = 0; i < 16; i++){
            const int mt = i >> 2, r = i & 3;
            rz[i] = rzp[(mt*16 + r)*RZS];
            nn[i] = nnp[(mt*16 + r)*NSS];
        }
        #pragma unroll
        for (int i = 0; i < 16; i++){
            const int mt = i >> 2, r = i & 3;
            const float xr = bf2f((u16)(rz[i] & 0xFFFFu));
            const float xz = bf2f((u16)(rz[i] >> 16));
            const float xn = bf2f(nn[i]);
            const float rg = sigm_hw(xr + acc[mt][0][r]);
            const float zg = sigm_hw(xz + acc[mt][1][r]);
            const float ng = tanh_hw(fmaf(rg, acc[mt][2][r], xn));
            hreg[i] = fmaf(zg, hreg[i] - ng, ng);
        }
        if (t + 1 < NW){
            __syncthreads();                 // all h_t reads (MFMA phase) complete
            #pragma unroll
            for (int mt = 0; mt < 4; mt++)
                #pragma unroll
                for (int r = 0; r < 4; r++){
                    const int rit = mt*16 + q*4 + r;
                    h_lds[rit*HS + col] = f2bf_rh(hreg[mt*4 + r]);
                }
            __syncthreads();                 // h_{t+1} visible to all waves
        }
    }
    // epilogue: mask, store hidden (bf16), BN partial sums
    float sum = 0.0f, sumsq = 0.0f;
    #pragma unroll
    for (int mt = 0; mt < 4; mt++)
        #pragma unroll
        for (int r = 0; r < 4; r++){
            const int rit = mt*16 + q*4 + r;
            const float hm = hreg[mt*4 + r] * maskv[rit];
            hidden[(size_t)(mb*MRR + rit)*512 + dir*NH + col] = f2bf(hm);
            sum += hm; sumsq += hm*hm;
        }
    // reduce across q (lanes l15, l15+16, l15+32, l15+48 share a col)
    sum   += __shfl_xor(sum, 16);   sumsq += __shfl_xor(sumsq, 16);
    sum   += __shfl_xor(sum, 32);   sumsq += __shfl_xor(sumsq, 32);
    if (q == 0){
        atomicAdd(&bnSum[dir*NH + col], sum);
        atomicAdd(&bnSumSq[dir*NH + col], sumsq);
    }
}

// ---------------- BN finalize ----------------
__global__ void bnfin_kernel(const float* __restrict__ bnSum, const float* __restrict__ bnSumSq,
                             const float* __restrict__ gamma, const float* __restrict__ beta,
                             float* __restrict__ bnScale, float* __restrict__ bnShift)
{
    const int c = blockIdx.x*blockDim.x + threadIdx.x;
    if (c < 512){
        const float mu  = bnSum[c]   * (1.0f/16384.0f);
        const float var = bnSumSq[c] * (1.0f/16384.0f) - mu*mu;
        const float inv = rsqrtf(var + 1e-5f);
        const float sc  = gamma[c]*inv;
        bnScale[c] = sc;
        bnShift[c] = beta[c] - mu*sc;
    }
}

// ---------------- MLP + mask + max-pool ----------------
__global__ __launch_bounds__(512, 4)
void mlp_kernel(const int* __restrict__ x, const u16* __restrict__ hidden,
                const u16* __restrict__ mlpW_p, const float* __restrict__ bnScale,
                const float* __restrict__ bnShift, const float* __restrict__ mlp_b,
                unsigned* __restrict__ pooled_u)
{
    __shared__ u16 a_lds[MRE*520];
    __shared__ float maskv[MRE];
    const int tid = threadIdx.x;
    const int mb  = blockIdx.x;     // 0..511
    if (tid < MRE) maskv[tid] = (x[mb*MRE + tid] > 0) ? 1.0f : 0.0f;
    __syncthreads();
    {
        const int row = tid >> 4, jj = tid & 15;
        const float m = maskv[row];
        const u16* src = hidden + (size_t)(mb*MRE + row)*512;
        u16* dst = a_lds + row*520;
        for (int c4 = jj; c4 < 128; c4 += 16){
            ushort4 v = ((const ushort4*)src)[c4];
            const int c = c4*4;
            float4 sc = *(const float4*)(bnScale + c);
            float4 sh = *(const float4*)(bnShift + c);
            ushort4 o;
            o.x = f2bf((bf2f(v.x)*sc.x + sh.x)*m);
            o.y = f2bf((bf2f(v.y)*sc.y + sh.y)*m);
            o.z = f2bf((bf2f(v.z)*sc.z + sh.z)*m);
            o.w = f2bf((bf2f(v.w)*sc.w + sh.w)*m);
            *(ushort4*)(dst + c) = o;
        }
    }
    __syncthreads();

    const int lane = tid & 63, wv = tid >> 6, l31 = lane & 31, q = lane >> 5;
    f32x16 acc[2];
    #pragma unroll
    for (int g = 0; g < 2; g++)
        #pragma unroll
        for (int i = 0; i < 16; i++) acc[g][i] = 0.0f;

    const u16* a0p = a_lds + l31*520 + q*8;
    const u16* b0p = mlpW_p + (size_t)(wv*64 +      l31)*512 + q*8;
    const u16* b1p = mlpW_p + (size_t)(wv*64 + 32 + l31)*512 + q*8;

    #pragma unroll 4
    for (int kc = 0; kc < 32; kc++){
        const int ko = kc*16;
        bf16x8 a0 = *(const bf16x8*)(a0p + ko);
        bf16x8 b0 = *(const bf16x8*)(b0p + ko);
        bf16x8 b1 = *(const bf16x8*)(b1p + ko);
        acc[0] = MFMA32(a0,b0,acc[0],0,0,0);
        acc[1] = MFMA32(a0,b1,acc[1],0,0,0);
    }

    const int bidx = mb >> 4;
    #pragma unroll
    for (int nt = 0; nt < 2; nt++){
        const int colg = wv*64 + nt*32 + l31;
        const float bias = mlp_b[colg];
        float mx = -3.4e38f;
        #pragma unroll
        for (int r = 0; r < 16; r++){
            const int rit = (r&3) + 8*(r>>2) + 4*q;
            const float m = maskv[rit];
            const float v = (acc[nt][r] + bias)*m + (m - 1.0f)*65500.0f;
            mx = fmaxf(mx, v);
        }
        mx = fmaxf(mx, __shfl_xor(mx, 32));
        if (q == 0) atomicMax(&pooled_u[bidx*512 + colg], fkey(mx));
    }
}

// ---------------- final linear [32x512] @ [512x2] ----------------
__global__ void final_kernel(const unsigned* __restrict__ pooled_u,
                             const float* __restrict__ linW, const float* __restrict__ linb,
                             float* __restrict__ out)
{
    const int b = blockIdx.x;       // 32
    const int lane = threadIdx.x;   // 64
    float s0 = 0.0f, s1 = 0.0f;
    for (int c = lane; c < 512; c += 64){
        const unsigned u = pooled_u[b*512 + c];
        const unsigned bits = (u & 0x80000000u) ? (u ^ 0x80000000u) : ~u;
        const float f = __uint_as_float(bits);
        s0 += f * linW[c];
        s1 += f * linW[512 + c];
    }
    #pragma unroll
    for (int off = 32; off > 0; off >>= 1){
        s0 += __shfl_xor(s0, off);
        s1 += __shfl_xor(s1, off);
    }
    if (lane == 0){ out[2*b] = s0 + linb[0]; out[2*b + 1] = s1 + linb[1]; }
}

extern "C" void kernel_launch(void* const* d_in, const int* in_sizes, int n_in,
                              void* d_out, int out_size, void* d_ws, size_t ws_size,
                              hipStream_t stream)
{
    const int*   x     = (const int*)  d_in[0];
    const float* emb   = (const float*)d_in[5];
    const float* Wih_f = (const float*)d_in[6];
    const float* Whh_f = (const float*)d_in[7];
    const float* bih_f = (const float*)d_in[8];
    const float* bhh_f = (const float*)d_in[9];
    const float* Wih_b = (const float*)d_in[10];
    const float* Whh_b = (const float*)d_in[11];
    const float* bih_b = (const float*)d_in[12];
    const float* bhh_b = (const float*)d_in[13];
    const float* gamma = (const float*)d_in[14];
    const float* beta  = (const float*)d_in[15];
    const float* mlpW  = (const float*)d_in[16];
    const float* mlpb  = (const float*)d_in[17];
    const float* linW  = (const float*)d_in[18];
    const float* linb  = (const float*)d_in[19];
    float* out = (float*)d_out;
    char* ws = (char*)d_ws;

    u16*   WihF_p  = (u16*)  (ws + 0);
    u16*   WihB_p  = (u16*)  (ws + 491520);
    u16*   WhhF_p  = (u16*)  (ws + 983040);      // fragment-packed, 393216 B
    u16*   WhhB_p  = (u16*)  (ws + 1376256);
    u16*   mlpW_p  = (u16*)  (ws + 1769472);
    float* bnSum   = (float*)(ws + 2293760);
    float* bnSumSq = (float*)(ws + 2295808);
    float* bnScale = (float*)(ws + 2297856);
    float* bnShift = (float*)(ws + 2299904);
    unsigned* pooled_u = (unsigned*)(ws + 2301952);
    u16*   hidden  = (u16*)  (ws + 2367488);     // 16384x512 bf16
    u32*   xprojRZ = (u32*)  (ws + 19144704);    // 16448x256 u32 (r|z<<16), 16842752 B
    u16*   xprojN  = (u16*)  (ws + 35987456);    // 16448x256 u16, 8421376 B

    prep_kernel<<<512, 256, 0, stream>>>(Wih_f, Wih_b, Whh_f, Whh_b, mlpW,
                                         WihF_p, WihB_p, WhhF_p, WhhB_p, mlpW_p,
                                         bnSum, bnSumSq, pooled_u);
    // forward direction
    eproj_kernel<<<514, 512, 0, stream>>>(x, emb, WihF_p, bih_f, bhh_f, xprojRZ, xprojN);
    recur_kernel<<<256, 1024, 0, stream>>>(x, xprojRZ, xprojN, WhhF_p, bhh_f, hidden, bnSum, bnSumSq, 0);
    // backward direction (reuses xproj buffers)
    eproj_kernel<<<514, 512, 0, stream>>>(x, emb, WihB_p, bih_b, bhh_b, xprojRZ, xprojN);
    recur_kernel<<<256, 1024, 0, stream>>>(x, xprojRZ, xprojN, WhhB_p, bhh_b, hidden, bnSum, bnSumSq, 1);

    bnfin_kernel<<<2, 256, 0, stream>>>(bnSum, bnSumSq, gamma, beta, bnScale, bnShift);
    mlp_kernel<<<512, 512, 0, stream>>>(x, hidden, mlpW_p, bnScale, bnShift, mlpb, pooled_u);
    final_kernel<<<32, 64, 0, stream>>>(pooled_u, linW, linb, out);
}